// Round 19
// baseline (166.127 us; speedup 1.0000x reference)
//
#include <hip/hip_runtime.h>

#define DD 64        // embedding dim
#define RPCB 1024    // rows per coarse bucket
#define CBSH 10      // log2(RPCB)
#define NBLK_P 256   // partition blocks (p1/p2), 1024 threads each

static inline size_t align16(size_t x) { return (x + 15) & ~(size_t)15; }

__device__ __forceinline__ unsigned bf16rn(float f) {
    unsigned u = __float_as_uint(f);
    return (u + 0x7fffu + ((u >> 16) & 1u)) >> 16;   // RNE
}

typedef __attribute__((ext_vector_type(8))) short bf16x8;  // 8 bf16 (4 VGPRs)
typedef __attribute__((ext_vector_type(4))) float f32x4;   // 4 fp32 acc

#define VAL_SCALE 32767.0f
#define VAL_INV   (1.0f / 32767.0f)

// ---------------- P1: per-block histogram over coarse buckets ----------------
__global__ __launch_bounds__(1024) void p1_hist(
    const int* __restrict__ srows, const int* __restrict__ irows,
    int* __restrict__ hmat, int ES, int EI, int U, int CB, int EPB)
{
    __shared__ int hist[256];          // CB <= 256 (U <= 131072)
    const int b = blockIdx.x, t = threadIdx.x;
    for (int i = t; i < CB; i += 1024) hist[i] = 0;
    __syncthreads();
    const int e0 = b * EPB, e1 = min(e0 + EPB, ES + EI);
    for (int e = e0 + t; e < e1; e += 1024) {
        int row = (e < ES) ? srows[e] : U + irows[e - ES];
        atomicAdd(&hist[row >> CBSH], 1);
    }
    __syncthreads();
    for (int i = t; i < CB; i += 1024) hmat[(size_t)i * NBLK_P + b] = hist[i];
}

// ---------------- scan helpers (2 kernels: partial, then add-with-inline-top) ----------------
__global__ __launch_bounds__(256) void scan_partial(
    const int* __restrict__ in, int* __restrict__ out, int* __restrict__ bsums, int n)
{
    __shared__ int sh[256];
    int base = blockIdx.x * 2048 + threadIdx.x * 8;
    int v[8];
    int tsum = 0;
    #pragma unroll
    for (int j = 0; j < 8; ++j) {
        int idx = base + j;
        int x = (idx < n) ? in[idx] : 0;
        v[j] = tsum;
        tsum += x;
    }
    sh[threadIdx.x] = tsum;
    __syncthreads();
    for (int off = 1; off < 256; off <<= 1) {
        int t = (threadIdx.x >= off) ? sh[threadIdx.x - off] : 0;
        __syncthreads();
        sh[threadIdx.x] += t;
        __syncthreads();
    }
    int texc = sh[threadIdx.x] - tsum;
    #pragma unroll
    for (int j = 0; j < 8; ++j) {
        int idx = base + j;
        if (idx < n) out[idx] = texc + v[j];
    }
    if (threadIdx.x == 255) bsums[blockIdx.x] = sh[255];
}

// adds the exclusive prefix of bsums (computed inline; nb is small, loads wave-uniform)
__global__ __launch_bounds__(256) void scan_add2(
    int* __restrict__ out, const int* __restrict__ bsums, int n)
{
    int i = blockIdx.x * 256 + threadIdx.x;
    if (i >= n) return;
    int blk = i >> 11;
    int pre = 0;
    for (int j = 0; j < blk; ++j) pre += bsums[j];
    out[i] += pre;
}

// ---------------- P2: partition scatter into per-(bucket,block) exclusive ranges ----------------
// bedges: .x = row_lo<<17 | col (sort key), .y = col | q15<<17 (final edge word)
__global__ __launch_bounds__(1024) void p2_scatter(
    const int* __restrict__ srows, const int* __restrict__ scols, const float* __restrict__ svals,
    const int* __restrict__ irows, const int* __restrict__ icols, const float* __restrict__ ivals,
    const int* __restrict__ hS, uint2* __restrict__ bedges,
    int ES, int EI, int U, int CB, int EPB)
{
    __shared__ int cur[256];
    const int b = blockIdx.x, t = threadIdx.x;
    for (int i = t; i < CB; i += 1024) cur[i] = hS[(size_t)i * NBLK_P + b];
    __syncthreads();
    const int e0 = b * EPB, e1 = min(e0 + EPB, ES + EI);
    for (int e = e0 + t; e < e1; e += 1024) {
        int row, col; float val;
        if (e < ES) { row = srows[e]; col = scols[e]; val = svals[e]; }
        else {
            int i = e - ES;
            row = U + irows[i]; col = icols[i]; val = ivals[i];
        }
        unsigned q = (unsigned)(val * VAL_SCALE + 0.5f);   // val in [0,1)
        int slot = atomicAdd(&cur[row >> CBSH], 1);
        bedges[slot] = make_uint2(((unsigned)(row & (RPCB - 1)) << 17) | (unsigned)col,
                                  (unsigned)col | (q << 17));
    }
}

// ---------------- P3: per-bucket finalize -> row_ptr + exact CSR slots (1024 thr) ----------------
__global__ __launch_bounds__(1024) void p3_fin(
    const uint2* __restrict__ bedges, const int* __restrict__ hS,
    int* __restrict__ row_ptr, unsigned* __restrict__ edges,
    int n2, int Etot, int CB)
{
    __shared__ int cnt[RPCB];
    __shared__ int sh[1024];
    const int cb = blockIdx.x, t = threadIdx.x;
    const int r0 = cb << CBSH;
    const int s = hS[(size_t)cb * NBLK_P];
    const int e = (cb == CB - 1) ? Etot : hS[(size_t)(cb + 1) * NBLK_P];

    cnt[t] = 0;
    __syncthreads();
    for (int i = s + t; i < e; i += 1024) atomicAdd(&cnt[bedges[i].x >> 17], 1);
    __syncthreads();

    int c = cnt[t];
    sh[t] = c;
    __syncthreads();
    for (int off = 1; off < 1024; off <<= 1) {
        int v = (t >= off) ? sh[t - off] : 0;
        __syncthreads();
        sh[t] += v;
        __syncthreads();
    }
    int v = s + sh[t] - c;              // exclusive slot base for local row t
    __syncthreads();
    cnt[t] = v;                         // becomes cursor
    int gr = r0 + t;
    if (gr < n2) row_ptr[gr] = v;
    if (cb == CB - 1 && t == 0) row_ptr[n2] = Etot;
    __syncthreads();

    for (int i = s + t; i < e; i += 1024) {
        uint2 ev = bedges[i];
        int slot = atomicAdd(&cnt[ev.x >> 17], 1);
        edges[slot] = ev.y;
    }
}

// ================= conv: quant tables + weight transpose, one launch =================
__global__ __launch_bounds__(256) void conv_all(
    const float* __restrict__ uemb, ushort* __restrict__ ubf,
    unsigned char* __restrict__ uq8, float* __restrict__ uscale, int U,
    const float* __restrict__ iemb, unsigned char* __restrict__ iq8,
    float* __restrict__ iscale, float* __restrict__ passI, int I,
    const float* __restrict__ w, ushort* __restrict__ wtb, int nw)
{
    int idx = blockIdx.x * 256 + threadIdx.x;
    const int qthreads = (U + I) * 8;
    if (idx < qthreads) {
        int row  = idx >> 3;
        int lane = idx & 7;
        bool isU = (row < U);
        int lrow = isU ? row : row - U;
        const float* src = (isU ? uemb : iemb) + ((size_t)lrow << 6) + lane * 8;
        float4 A = *reinterpret_cast<const float4*>(src);
        float4 B = *reinterpret_cast<const float4*>(src + 4);
        float m = fmaxf(fmaxf(fmaxf(fabsf(A.x), fabsf(A.y)), fmaxf(fabsf(A.z), fabsf(A.w))),
                        fmaxf(fmaxf(fabsf(B.x), fabsf(B.y)), fmaxf(fabsf(B.z), fabsf(B.w))));
        m = fmaxf(m, __shfl_xor(m, 1, 8));
        m = fmaxf(m, __shfl_xor(m, 2, 8));
        m = fmaxf(m, __shfl_xor(m, 4, 8));
        float inv = (m > 1e-30f) ? 127.0f / m : 0.0f;
        unsigned b0 = (unsigned)(__float2int_rn(A.x * inv) + 128);
        unsigned b1 = (unsigned)(__float2int_rn(A.y * inv) + 128);
        unsigned b2 = (unsigned)(__float2int_rn(A.z * inv) + 128);
        unsigned b3 = (unsigned)(__float2int_rn(A.w * inv) + 128);
        unsigned b4 = (unsigned)(__float2int_rn(B.x * inv) + 128);
        unsigned b5 = (unsigned)(__float2int_rn(B.y * inv) + 128);
        unsigned b6 = (unsigned)(__float2int_rn(B.z * inv) + 128);
        unsigned b7 = (unsigned)(__float2int_rn(B.w * inv) + 128);
        uint2 pk = make_uint2(b0 | (b1 << 8) | (b2 << 16) | (b3 << 24),
                              b4 | (b5 << 8) | (b6 << 16) | (b7 << 24));
        if (isU) {
            reinterpret_cast<uint2*>(uq8 + ((size_t)lrow << 6) + lane * 8)[0] = pk;
            if (lane == 0) uscale[lrow] = m / 127.0f;
            uint4 r;
            r.x = bf16rn(A.x) | (bf16rn(A.y) << 16);
            r.y = bf16rn(A.z) | (bf16rn(A.w) << 16);
            r.z = bf16rn(B.x) | (bf16rn(B.y) << 16);
            r.w = bf16rn(B.z) | (bf16rn(B.w) << 16);
            *reinterpret_cast<uint4*>(ubf + ((size_t)lrow << 6) + lane * 8) = r;
        } else {
            reinterpret_cast<uint2*>(iq8 + ((size_t)lrow << 6) + lane * 8)[0] = pk;
            if (lane == 0) iscale[lrow] = m / 127.0f;
            float* q = passI + ((size_t)lrow << 6) + lane * 8;
            *reinterpret_cast<float4*>(q)     = A;
            *reinterpret_cast<float4*>(q + 4) = B;
        }
    } else {
        int widx = idx - qthreads;
        if (widx < nw) {
            int l = widx >> 13;
            int r = widx & 8191;
            int c = r >> 7;          // col 0..63
            int k = r & 127;         // k   0..127
            wtb[widx] = (ushort)bf16rn(w[(size_t)l * 8192 + k * 64 + c]);
        }
    }
}

// ================= SpMM (CSR row-gather, int8 rowscale source, fp32 accumulate) =================
__device__ __forceinline__ void fma_i8(float4& a0, float4& a1, float& ssum, float veff, uint2 x)
{
    ssum += veff;
    a0.x += veff * (float)(x.x & 0xffu);
    a0.y += veff * (float)((x.x >> 8) & 0xffu);
    a0.z += veff * (float)((x.x >> 16) & 0xffu);
    a0.w += veff * (float)(x.x >> 24);
    a1.x += veff * (float)(x.y & 0xffu);
    a1.y += veff * (float)((x.y >> 8) & 0xffu);
    a1.z += veff * (float)((x.y >> 16) & 0xffu);
    a1.w += veff * (float)(x.y >> 24);
}

// MODE 0: write bf16; MODE 1: add into fp32 out
template <int MODE>
__global__ __launch_bounds__(256) void spmm_i8(
    const int* __restrict__ row_ptr, const unsigned* __restrict__ edges,
    const unsigned char* __restrict__ q8,   // int8 [nx,64] biased
    const float* __restrict__ scalef,       // [nx]
    ushort* __restrict__ outb, float* __restrict__ outf, int nrows)
{
    int g    = (blockIdx.x * 256 + threadIdx.x) >> 3;
    int lane = threadIdx.x & 7;
    if (g >= nrows) return;
    int s = row_ptr[g], e = row_ptr[g + 1];
    float4 a0 = make_float4(0.f, 0.f, 0.f, 0.f);
    float4 a1 = make_float4(0.f, 0.f, 0.f, 0.f);
    float ssum = 0.f;
    int i = s;
    for (; i + 3 < e; i += 4) {
        unsigned e0 = edges[i], e1 = edges[i + 1], e2 = edges[i + 2], e3 = edges[i + 3];
        unsigned c0 = e0 & 0x1FFFFu, c1 = e1 & 0x1FFFFu, c2 = e2 & 0x1FFFFu, c3 = e3 & 0x1FFFFu;
        uint2 x0 = *reinterpret_cast<const uint2*>(q8 + ((size_t)c0 << 6) + lane * 8);
        uint2 x1 = *reinterpret_cast<const uint2*>(q8 + ((size_t)c1 << 6) + lane * 8);
        uint2 x2 = *reinterpret_cast<const uint2*>(q8 + ((size_t)c2 << 6) + lane * 8);
        uint2 x3 = *reinterpret_cast<const uint2*>(q8 + ((size_t)c3 << 6) + lane * 8);
        float v0 = (float)(e0 >> 17) * VAL_INV * scalef[c0];
        float v1 = (float)(e1 >> 17) * VAL_INV * scalef[c1];
        float v2 = (float)(e2 >> 17) * VAL_INV * scalef[c2];
        float v3 = (float)(e3 >> 17) * VAL_INV * scalef[c3];
        fma_i8(a0, a1, ssum, v0, x0);
        fma_i8(a0, a1, ssum, v1, x1);
        fma_i8(a0, a1, ssum, v2, x2);
        fma_i8(a0, a1, ssum, v3, x3);
    }
    for (; i < e; ++i) {
        unsigned e0 = edges[i];
        unsigned c0 = e0 & 0x1FFFFu;
        uint2 x0 = *reinterpret_cast<const uint2*>(q8 + ((size_t)c0 << 6) + lane * 8);
        float v0 = (float)(e0 >> 17) * VAL_INV * scalef[c0];
        fma_i8(a0, a1, ssum, v0, x0);
    }
    float bias = 128.f * ssum;
    a0.x -= bias; a0.y -= bias; a0.z -= bias; a0.w -= bias;
    a1.x -= bias; a1.y -= bias; a1.z -= bias; a1.w -= bias;
    if (MODE == 0) {
        uint4 pk;
        pk.x = bf16rn(a0.x) | (bf16rn(a0.y) << 16);
        pk.y = bf16rn(a0.z) | (bf16rn(a0.w) << 16);
        pk.z = bf16rn(a1.x) | (bf16rn(a1.y) << 16);
        pk.w = bf16rn(a1.z) | (bf16rn(a1.w) << 16);
        *reinterpret_cast<uint4*>(outb + ((size_t)g << 6) + lane * 8) = pk;
    } else {
        float* o = outf + ((size_t)g << 6) + lane * 8;
        float4 c0 = *reinterpret_cast<const float4*>(o);
        float4 c1 = *reinterpret_cast<const float4*>(o + 4);
        a0.x += c0.x; a0.y += c0.y; a0.z += c0.z; a0.w += c0.w;
        a1.x += c1.x; a1.y += c1.y; a1.z += c1.z; a1.w += c1.w;
        *reinterpret_cast<float4*>(o)     = a0;
        *reinterpret_cast<float4*>(o + 4) = a1;
    }
}

// ================= MFMA concat-GEMM =================
// Block = 256 threads = 4 waves; 64 rows/block. A-frags from global; W^T bf16 in LDS,
// granule-swizzled. C/D mapping: col=lane&15, row=(lane>>4)*4+reg [HW-verified].
// !FINAL epilogue: LDS-stage the 64x64 tile, then quantize (bf16 + int8 rowscale tables).
template<bool FINAL>
__global__ __launch_bounds__(256) void gemm_mfma(
    const ushort* __restrict__ abf,   // bf16 [U,64] spmm result
    const ushort* __restrict__ bbf,   // bf16 [U,64] prev u
    const ushort* __restrict__ wtb,   // bf16 W^T [64,128] for this layer
    float* __restrict__ outf,         // FINAL: fp32 [U,64]
    ushort* __restrict__ outb,        // !FINAL: bf16 [U,64]
    unsigned char* __restrict__ q8,   // !FINAL: int8 [U,64]
    float* __restrict__ scale,        // !FINAL: [U]
    int U)
{
    __shared__ ushort sWt[64 * 128];  // 16 KB; reused as sOut[64][72] in epilogue
    const int t = threadIdx.x;

    for (int i = t; i < 1024; i += 256) {
        int c = i >> 4, g = i & 15;
        uint4 v = *reinterpret_cast<const uint4*>(wtb + (size_t)c * 128 + g * 8);
        int gp = g ^ (c & 7);
        *reinterpret_cast<uint4*>(&sWt[c * 128 + gp * 8]) = v;
    }
    __syncthreads();

    const int w    = t >> 6;
    const int l    = t & 63;
    const int l16  = l & 15;
    const int ksub = l >> 4;
    const int grow_base = blockIdx.x * 64 + w * 16;
    const int arow = min(grow_base + l16, U - 1);

    f32x4 acc[4] = {f32x4{0,0,0,0}, f32x4{0,0,0,0}, f32x4{0,0,0,0}, f32x4{0,0,0,0}};

    #pragma unroll
    for (int kk = 0; kk < 4; ++kk) {
        const int kof = kk * 32 + ksub * 8;
        const ushort* asrc = (kk < 2) ? (abf + ((size_t)arow << 6) + kof)
                                      : (bbf + ((size_t)arow << 6) + (kof - 64));
        bf16x8 afrag = *reinterpret_cast<const bf16x8*>(asrc);
        #pragma unroll
        for (int ct = 0; ct < 4; ++ct) {
            int c  = ct * 16 + l16;
            int g  = kk * 4 + ksub;
            int gp = g ^ (c & 7);
            bf16x8 bfrag = *reinterpret_cast<const bf16x8*>(&sWt[c * 128 + gp * 8]);
            acc[ct] = __builtin_amdgcn_mfma_f32_16x16x32_bf16(afrag, bfrag, acc[ct], 0, 0, 0);
        }
    }

    if (FINAL) {
        #pragma unroll
        for (int ct = 0; ct < 4; ++ct) {
            #pragma unroll
            for (int j = 0; j < 4; ++j) {
                int grow = grow_base + ksub * 4 + j;
                int gcol = ct * 16 + l16;
                if (grow < U) outf[((size_t)grow << 6) + gcol] = acc[ct][j];
            }
        }
    } else {
        __syncthreads();                   // sWt reads done; reuse as sOut
        ushort* sOut = sWt;                // [64][72] padded
        #pragma unroll
        for (int ct = 0; ct < 4; ++ct) {
            #pragma unroll
            for (int j = 0; j < 4; ++j) {
                int rloc = w * 16 + ksub * 4 + j;
                int col  = ct * 16 + l16;
                sOut[rloc * 72 + col] = (ushort)bf16rn(acc[ct][j]);
            }
        }
        __syncthreads();
        #pragma unroll
        for (int pass = 0; pass < 2; ++pass) {
            int rloc = pass * 32 + (t >> 3);
            int lane = t & 7;
            int grow = blockIdx.x * 64 + rloc;
            uint4 x = *reinterpret_cast<const uint4*>(&sOut[rloc * 72 + lane * 8]);
            float v0 = __uint_as_float(x.x << 16), v1 = __uint_as_float(x.x & 0xffff0000u);
            float v2 = __uint_as_float(x.y << 16), v3 = __uint_as_float(x.y & 0xffff0000u);
            float v4 = __uint_as_float(x.z << 16), v5 = __uint_as_float(x.z & 0xffff0000u);
            float v6 = __uint_as_float(x.w << 16), v7 = __uint_as_float(x.w & 0xffff0000u);
            float m = fmaxf(fmaxf(fmaxf(fabsf(v0), fabsf(v1)), fmaxf(fabsf(v2), fabsf(v3))),
                            fmaxf(fmaxf(fabsf(v4), fabsf(v5)), fmaxf(fabsf(v6), fabsf(v7))));
            m = fmaxf(m, __shfl_xor(m, 1, 8));
            m = fmaxf(m, __shfl_xor(m, 2, 8));
            m = fmaxf(m, __shfl_xor(m, 4, 8));
            float inv = (m > 1e-30f) ? 127.0f / m : 0.0f;
            unsigned b0 = (unsigned)(__float2int_rn(v0 * inv) + 128);
            unsigned b1 = (unsigned)(__float2int_rn(v1 * inv) + 128);
            unsigned b2 = (unsigned)(__float2int_rn(v2 * inv) + 128);
            unsigned b3 = (unsigned)(__float2int_rn(v3 * inv) + 128);
            unsigned b4 = (unsigned)(__float2int_rn(v4 * inv) + 128);
            unsigned b5 = (unsigned)(__float2int_rn(v5 * inv) + 128);
            unsigned b6 = (unsigned)(__float2int_rn(v6 * inv) + 128);
            unsigned b7 = (unsigned)(__float2int_rn(v7 * inv) + 128);
            uint2 pk = make_uint2(b0 | (b1 << 8) | (b2 << 16) | (b3 << 24),
                                  b4 | (b5 << 8) | (b6 << 16) | (b7 << 24));
            if (grow < U) {
                *reinterpret_cast<uint4*>(outb + ((size_t)grow << 6) + lane * 8) = x;
                reinterpret_cast<uint2*>(q8 + ((size_t)grow << 6) + lane * 8)[0] = pk;
                if (lane == 0) scale[grow] = m / 127.0f;
            }
        }
    }
}

extern "C" void kernel_launch(void* const* d_in, const int* in_sizes, int n_in,
                              void* d_out, int out_size, void* d_ws, size_t ws_size,
                              hipStream_t stream)
{
    const float* user_emb    = (const float*)d_in[0];
    const float* item_emb    = (const float*)d_in[1];
    const float* weights     = (const float*)d_in[2];
    const float* social_vals = (const float*)d_in[3];
    const float* inter_vals  = (const float*)d_in[4];
    const int*   social_rows = (const int*)d_in[5];
    const int*   social_cols = (const int*)d_in[6];
    const int*   inter_rows  = (const int*)d_in[7];
    const int*   inter_cols  = (const int*)d_in[8];

    const int D  = DD;
    const int U  = in_sizes[0] / D;
    const int I  = in_sizes[1] / D;
    const int L  = in_sizes[2] / (2 * D * D);
    const int ES = in_sizes[3];
    const int EI = in_sizes[4];

    float* out      = (float*)d_out;           // final_u [U, D]
    float* out_item = out + (size_t)U * D;     // item_emb passthrough [I, D]

    // ---- workspace layout ----
    char* p = (char*)d_ws;
    size_t off = 0;
    auto take = [&](size_t bytes) { char* r = p + off; off += align16(bytes); return r; };

    const int n2   = 2 * U;
    const int CB   = (n2 + RPCB - 1) >> CBSH;       // coarse buckets (<= 256)
    const int Etot = ES + EI;
    const int EPB  = (Etot + NBLK_P - 1) / NBLK_P;  // edges per partition block
    const int NH   = CB * NBLK_P;

    int*           row_ptr = (int*)take((size_t)(n2 + 1) * sizeof(int));
    int*           hmat    = (int*)take((size_t)NH * sizeof(int));
    int*           hS      = (int*)take((size_t)NH * sizeof(int));
    int*           bsums   = (int*)take(1024 * sizeof(int));
    unsigned*      edges   = (unsigned*)take((size_t)Etot * sizeof(unsigned));
    uint2*         bedges  = (uint2*)take((size_t)Etot * sizeof(uint2));
    ushort*        ubf     = (ushort*)take((size_t)U * D * sizeof(ushort));
    unsigned char* uq8     = (unsigned char*)take((size_t)U * D);
    float*         uscale  = (float*)take((size_t)U * sizeof(float));
    unsigned char* iq8     = (unsigned char*)take((size_t)I * D);
    float*         iscale  = (float*)take((size_t)I * sizeof(float));
    ushort*        wtb     = (ushort*)take((size_t)L * 2 * D * D * sizeof(ushort));
    ushort*        tmpA_bf = (ushort*)take((size_t)U * D * sizeof(ushort));
    ushort*        uB_bf   = (ushort*)take((size_t)U * D * sizeof(ushort));
    ushort*        uC_bf   = (ushort*)take((size_t)U * D * sizeof(ushort));
    unsigned char* uB_q8   = (unsigned char*)take((size_t)U * D);
    unsigned char* uC_q8   = (unsigned char*)take((size_t)U * D);
    float*         uB_sc   = (float*)take((size_t)U * sizeof(float));
    float*         uC_sc   = (float*)take((size_t)U * sizeof(float));

    // ---- CSR build: partition histogram -> scan (2 kernels) -> scatter -> finalize ----
    p1_hist<<<NBLK_P, 1024, 0, stream>>>(social_rows, inter_rows, hmat, ES, EI, U, CB, EPB);
    const int nb = (NH + 2047) / 2048;
    scan_partial<<<nb, 256, 0, stream>>>(hmat, hS, bsums, NH);
    scan_add2<<<(NH + 255) / 256, 256, 0, stream>>>(hS, bsums, NH);
    p2_scatter<<<NBLK_P, 1024, 0, stream>>>(
        social_rows, social_cols, social_vals,
        inter_rows, inter_cols, inter_vals,
        hS, bedges, ES, EI, U, CB, EPB);
    p3_fin<<<CB, 1024, 0, stream>>>(bedges, hS, row_ptr, edges, n2, Etot, CB);

    // ---- tables + weight transpose (one launch) ----
    const int nw = L * 2 * D * D;
    const int convthreads = (U + I) * 8 + nw;
    conv_all<<<(convthreads + 255) / 256, 256, 0, stream>>>(
        user_emb, ubf, uq8, uscale, U, item_emb, iq8, iscale, out_item, I,
        weights, wtb, nw);

    // ---- layers ----
    const int spmm_grid = ((U * 8) + 255) / 256;
    const int gemm_grid = (U + 63) / 64;
    const ushort*        uprev_bf = ubf;
    const unsigned char* uprev_q8 = uq8;
    const float*         uprev_sc = uscale;
    int which = 0;
    for (int k = 0; k < L; ++k) {
        const ushort* wk = wtb + (size_t)k * 2 * D * D;
        spmm_i8<0><<<spmm_grid, 256, 0, stream>>>(
            row_ptr, edges, uprev_q8, uprev_sc, tmpA_bf, (float*)nullptr, U);
        if (k == L - 1) {
            gemm_mfma<true><<<gemm_grid, 256, 0, stream>>>(
                tmpA_bf, uprev_bf, wk, out, (ushort*)nullptr,
                (unsigned char*)nullptr, (float*)nullptr, U);
        } else {
            ushort*        nbf = which ? uC_bf : uB_bf;
            unsigned char* nq8 = which ? uC_q8 : uB_q8;
            float*         nsc = which ? uC_sc : uB_sc;
            gemm_mfma<false><<<gemm_grid, 256, 0, stream>>>(
                tmpA_bf, uprev_bf, wk, (float*)nullptr, nbf, nq8, nsc, U);
            uprev_bf = nbf;
            uprev_q8 = nq8;
            uprev_sc = nsc;
            which ^= 1;
        }
    }

    // final_u += A_inter @ item_emb (int8 gather, fp32 accumulate into d_out)
    spmm_i8<1><<<spmm_grid, 256, 0, stream>>>(
        row_ptr + U, edges, iq8, iscale, (ushort*)nullptr, out, U);
}

// Round 20
// 165.525 us; speedup vs baseline: 1.0036x; 1.0036x over previous
//
#include <hip/hip_runtime.h>

#define DD 64        // embedding dim
#define RPCB 1024    // rows per coarse bucket
#define CBSH 10      // log2(RPCB)
#define NBLK_P 256   // partition blocks (p1/p2), 1024 threads each

static inline size_t align16(size_t x) { return (x + 15) & ~(size_t)15; }

__device__ __forceinline__ unsigned bf16rn(float f) {
    unsigned u = __float_as_uint(f);
    return (u + 0x7fffu + ((u >> 16) & 1u)) >> 16;   // RNE
}

typedef __attribute__((ext_vector_type(8))) short bf16x8;  // 8 bf16 (4 VGPRs)
typedef __attribute__((ext_vector_type(4))) float f32x4;   // 4 fp32 acc

#define VAL_SCALE 32767.0f
#define VAL_INV   (1.0f / 32767.0f)

// ---------------- P1: per-block histogram over coarse buckets ----------------
__global__ __launch_bounds__(1024) void p1_hist(
    const int* __restrict__ srows, const int* __restrict__ irows,
    int* __restrict__ hmat, int ES, int EI, int U, int CB, int EPB)
{
    __shared__ int hist[256];          // CB <= 256 (U <= 131072)
    const int b = blockIdx.x, t = threadIdx.x;
    for (int i = t; i < CB; i += 1024) hist[i] = 0;
    __syncthreads();
    const int e0 = b * EPB, e1 = min(e0 + EPB, ES + EI);
    for (int e = e0 + t; e < e1; e += 1024) {
        int row = (e < ES) ? srows[e] : U + irows[e - ES];
        atomicAdd(&hist[row >> CBSH], 1);
    }
    __syncthreads();
    for (int i = t; i < CB; i += 1024) hmat[(size_t)i * NBLK_P + b] = hist[i];
}

// ---------------- scan helpers (2 kernels: partial, then add-with-inline-top) ----------------
__global__ __launch_bounds__(256) void scan_partial(
    const int* __restrict__ in, int* __restrict__ out, int* __restrict__ bsums, int n)
{
    __shared__ int sh[256];
    int base = blockIdx.x * 2048 + threadIdx.x * 8;
    int v[8];
    int tsum = 0;
    #pragma unroll
    for (int j = 0; j < 8; ++j) {
        int idx = base + j;
        int x = (idx < n) ? in[idx] : 0;
        v[j] = tsum;
        tsum += x;
    }
    sh[threadIdx.x] = tsum;
    __syncthreads();
    for (int off = 1; off < 256; off <<= 1) {
        int t = (threadIdx.x >= off) ? sh[threadIdx.x - off] : 0;
        __syncthreads();
        sh[threadIdx.x] += t;
        __syncthreads();
    }
    int texc = sh[threadIdx.x] - tsum;
    #pragma unroll
    for (int j = 0; j < 8; ++j) {
        int idx = base + j;
        if (idx < n) out[idx] = texc + v[j];
    }
    if (threadIdx.x == 255) bsums[blockIdx.x] = sh[255];
}

// adds the exclusive prefix of bsums (computed inline; nb is small, loads wave-uniform)
__global__ __launch_bounds__(256) void scan_add2(
    int* __restrict__ out, const int* __restrict__ bsums, int n)
{
    int i = blockIdx.x * 256 + threadIdx.x;
    if (i >= n) return;
    int blk = i >> 11;
    int pre = 0;
    for (int j = 0; j < blk; ++j) pre += bsums[j];
    out[i] += pre;
}

// ---------------- P2: partition scatter into per-(bucket,block) exclusive ranges ----------------
// bedges: .x = row_lo<<17 | col (sort key), .y = col | q15<<17 (final edge word)
__global__ __launch_bounds__(1024) void p2_scatter(
    const int* __restrict__ srows, const int* __restrict__ scols, const float* __restrict__ svals,
    const int* __restrict__ irows, const int* __restrict__ icols, const float* __restrict__ ivals,
    const int* __restrict__ hS, uint2* __restrict__ bedges,
    int ES, int EI, int U, int CB, int EPB)
{
    __shared__ int cur[256];
    const int b = blockIdx.x, t = threadIdx.x;
    for (int i = t; i < CB; i += 1024) cur[i] = hS[(size_t)i * NBLK_P + b];
    __syncthreads();
    const int e0 = b * EPB, e1 = min(e0 + EPB, ES + EI);
    for (int e = e0 + t; e < e1; e += 1024) {
        int row, col; float val;
        if (e < ES) { row = srows[e]; col = scols[e]; val = svals[e]; }
        else {
            int i = e - ES;
            row = U + irows[i]; col = icols[i]; val = ivals[i];
        }
        unsigned q = (unsigned)(val * VAL_SCALE + 0.5f);   // val in [0,1)
        int slot = atomicAdd(&cur[row >> CBSH], 1);
        bedges[slot] = make_uint2(((unsigned)(row & (RPCB - 1)) << 17) | (unsigned)col,
                                  (unsigned)col | (q << 17));
    }
}

// ---------------- P3: per-bucket finalize -> row_ptr + exact CSR slots (1024 thr) ----------------
__global__ __launch_bounds__(1024) void p3_fin(
    const uint2* __restrict__ bedges, const int* __restrict__ hS,
    int* __restrict__ row_ptr, unsigned* __restrict__ edges,
    int n2, int Etot, int CB)
{
    __shared__ int cnt[RPCB];
    __shared__ int sh[1024];
    const int cb = blockIdx.x, t = threadIdx.x;
    const int r0 = cb << CBSH;
    const int s = hS[(size_t)cb * NBLK_P];
    const int e = (cb == CB - 1) ? Etot : hS[(size_t)(cb + 1) * NBLK_P];

    cnt[t] = 0;
    __syncthreads();
    for (int i = s + t; i < e; i += 1024) atomicAdd(&cnt[bedges[i].x >> 17], 1);
    __syncthreads();

    int c = cnt[t];
    sh[t] = c;
    __syncthreads();
    for (int off = 1; off < 1024; off <<= 1) {
        int v = (t >= off) ? sh[t - off] : 0;
        __syncthreads();
        sh[t] += v;
        __syncthreads();
    }
    int v = s + sh[t] - c;              // exclusive slot base for local row t
    __syncthreads();
    cnt[t] = v;                         // becomes cursor
    int gr = r0 + t;
    if (gr < n2) row_ptr[gr] = v;
    if (cb == CB - 1 && t == 0) row_ptr[n2] = Etot;
    __syncthreads();

    for (int i = s + t; i < e; i += 1024) {
        uint2 ev = bedges[i];
        int slot = atomicAdd(&cnt[ev.x >> 17], 1);
        edges[slot] = ev.y;
    }
}

// ================= conv: quant tables + weight transpose, one launch =================
__global__ __launch_bounds__(256) void conv_all(
    const float* __restrict__ uemb, ushort* __restrict__ ubf,
    unsigned char* __restrict__ uq8, float* __restrict__ uscale, int U,
    const float* __restrict__ iemb, unsigned char* __restrict__ iq8,
    float* __restrict__ iscale, float* __restrict__ passI, int I,
    const float* __restrict__ w, ushort* __restrict__ wtb, int nw)
{
    int idx = blockIdx.x * 256 + threadIdx.x;
    const int qthreads = (U + I) * 8;
    if (idx < qthreads) {
        int row  = idx >> 3;
        int lane = idx & 7;
        bool isU = (row < U);
        int lrow = isU ? row : row - U;
        const float* src = (isU ? uemb : iemb) + ((size_t)lrow << 6) + lane * 8;
        float4 A = *reinterpret_cast<const float4*>(src);
        float4 B = *reinterpret_cast<const float4*>(src + 4);
        float m = fmaxf(fmaxf(fmaxf(fabsf(A.x), fabsf(A.y)), fmaxf(fabsf(A.z), fabsf(A.w))),
                        fmaxf(fmaxf(fabsf(B.x), fabsf(B.y)), fmaxf(fabsf(B.z), fabsf(B.w))));
        m = fmaxf(m, __shfl_xor(m, 1, 8));
        m = fmaxf(m, __shfl_xor(m, 2, 8));
        m = fmaxf(m, __shfl_xor(m, 4, 8));
        float inv = (m > 1e-30f) ? 127.0f / m : 0.0f;
        unsigned b0 = (unsigned)(__float2int_rn(A.x * inv) + 128);
        unsigned b1 = (unsigned)(__float2int_rn(A.y * inv) + 128);
        unsigned b2 = (unsigned)(__float2int_rn(A.z * inv) + 128);
        unsigned b3 = (unsigned)(__float2int_rn(A.w * inv) + 128);
        unsigned b4 = (unsigned)(__float2int_rn(B.x * inv) + 128);
        unsigned b5 = (unsigned)(__float2int_rn(B.y * inv) + 128);
        unsigned b6 = (unsigned)(__float2int_rn(B.z * inv) + 128);
        unsigned b7 = (unsigned)(__float2int_rn(B.w * inv) + 128);
        uint2 pk = make_uint2(b0 | (b1 << 8) | (b2 << 16) | (b3 << 24),
                              b4 | (b5 << 8) | (b6 << 16) | (b7 << 24));
        if (isU) {
            reinterpret_cast<uint2*>(uq8 + ((size_t)lrow << 6) + lane * 8)[0] = pk;
            if (lane == 0) uscale[lrow] = m / 127.0f;
            uint4 r;
            r.x = bf16rn(A.x) | (bf16rn(A.y) << 16);
            r.y = bf16rn(A.z) | (bf16rn(A.w) << 16);
            r.z = bf16rn(B.x) | (bf16rn(B.y) << 16);
            r.w = bf16rn(B.z) | (bf16rn(B.w) << 16);
            *reinterpret_cast<uint4*>(ubf + ((size_t)lrow << 6) + lane * 8) = r;
        } else {
            reinterpret_cast<uint2*>(iq8 + ((size_t)lrow << 6) + lane * 8)[0] = pk;
            if (lane == 0) iscale[lrow] = m / 127.0f;
            float* q = passI + ((size_t)lrow << 6) + lane * 8;
            *reinterpret_cast<float4*>(q)     = A;
            *reinterpret_cast<float4*>(q + 4) = B;
        }
    } else {
        int widx = idx - qthreads;
        if (widx < nw) {
            int l = widx >> 13;
            int r = widx & 8191;
            int c = r >> 7;          // col 0..63
            int k = r & 127;         // k   0..127
            wtb[widx] = (ushort)bf16rn(w[(size_t)l * 8192 + k * 64 + c]);
        }
    }
}

// ================= SpMM (CSR row-gather, int8 rowscale source, fp32 accumulate) =================
__device__ __forceinline__ void fma_i8(float4& a0, float4& a1, float& ssum, float veff, uint2 x)
{
    ssum += veff;
    a0.x += veff * (float)(x.x & 0xffu);
    a0.y += veff * (float)((x.x >> 8) & 0xffu);
    a0.z += veff * (float)((x.x >> 16) & 0xffu);
    a0.w += veff * (float)(x.x >> 24);
    a1.x += veff * (float)(x.y & 0xffu);
    a1.y += veff * (float)((x.y >> 8) & 0xffu);
    a1.z += veff * (float)((x.y >> 16) & 0xffu);
    a1.w += veff * (float)(x.y >> 24);
}

// MODE 0: write bf16; MODE 1: add into fp32 out
template <int MODE>
__global__ __launch_bounds__(256) void spmm_i8(
    const int* __restrict__ row_ptr, const unsigned* __restrict__ edges,
    const unsigned char* __restrict__ q8,   // int8 [nx,64] biased
    const float* __restrict__ scalef,       // [nx]
    ushort* __restrict__ outb, float* __restrict__ outf, int nrows)
{
    int g    = (blockIdx.x * 256 + threadIdx.x) >> 3;
    int lane = threadIdx.x & 7;
    if (g >= nrows) return;
    int s = row_ptr[g], e = row_ptr[g + 1];
    float4 a0 = make_float4(0.f, 0.f, 0.f, 0.f);
    float4 a1 = make_float4(0.f, 0.f, 0.f, 0.f);
    float ssum = 0.f;
    int i = s;
    for (; i + 3 < e; i += 4) {
        unsigned e0 = edges[i], e1 = edges[i + 1], e2 = edges[i + 2], e3 = edges[i + 3];
        unsigned c0 = e0 & 0x1FFFFu, c1 = e1 & 0x1FFFFu, c2 = e2 & 0x1FFFFu, c3 = e3 & 0x1FFFFu;
        uint2 x0 = *reinterpret_cast<const uint2*>(q8 + ((size_t)c0 << 6) + lane * 8);
        uint2 x1 = *reinterpret_cast<const uint2*>(q8 + ((size_t)c1 << 6) + lane * 8);
        uint2 x2 = *reinterpret_cast<const uint2*>(q8 + ((size_t)c2 << 6) + lane * 8);
        uint2 x3 = *reinterpret_cast<const uint2*>(q8 + ((size_t)c3 << 6) + lane * 8);
        float v0 = (float)(e0 >> 17) * VAL_INV * scalef[c0];
        float v1 = (float)(e1 >> 17) * VAL_INV * scalef[c1];
        float v2 = (float)(e2 >> 17) * VAL_INV * scalef[c2];
        float v3 = (float)(e3 >> 17) * VAL_INV * scalef[c3];
        fma_i8(a0, a1, ssum, v0, x0);
        fma_i8(a0, a1, ssum, v1, x1);
        fma_i8(a0, a1, ssum, v2, x2);
        fma_i8(a0, a1, ssum, v3, x3);
    }
    for (; i < e; ++i) {
        unsigned e0 = edges[i];
        unsigned c0 = e0 & 0x1FFFFu;
        uint2 x0 = *reinterpret_cast<const uint2*>(q8 + ((size_t)c0 << 6) + lane * 8);
        float v0 = (float)(e0 >> 17) * VAL_INV * scalef[c0];
        fma_i8(a0, a1, ssum, v0, x0);
    }
    float bias = 128.f * ssum;
    a0.x -= bias; a0.y -= bias; a0.z -= bias; a0.w -= bias;
    a1.x -= bias; a1.y -= bias; a1.z -= bias; a1.w -= bias;
    if (MODE == 0) {
        uint4 pk;
        pk.x = bf16rn(a0.x) | (bf16rn(a0.y) << 16);
        pk.y = bf16rn(a0.z) | (bf16rn(a0.w) << 16);
        pk.z = bf16rn(a1.x) | (bf16rn(a1.y) << 16);
        pk.w = bf16rn(a1.z) | (bf16rn(a1.w) << 16);
        *reinterpret_cast<uint4*>(outb + ((size_t)g << 6) + lane * 8) = pk;
    } else {
        float* o = outf + ((size_t)g << 6) + lane * 8;
        float4 c0 = *reinterpret_cast<const float4*>(o);
        float4 c1 = *reinterpret_cast<const float4*>(o + 4);
        a0.x += c0.x; a0.y += c0.y; a0.z += c0.z; a0.w += c0.w;
        a1.x += c1.x; a1.y += c1.y; a1.z += c1.z; a1.w += c1.w;
        *reinterpret_cast<float4*>(o)     = a0;
        *reinterpret_cast<float4*>(o + 4) = a1;
    }
}

// ================= MFMA concat-GEMM =================
// Block = 256 threads = 4 waves; 64 rows/block. A-frags from global; W^T bf16 in LDS,
// granule-swizzled. C/D mapping: col=lane&15, row=(lane>>4)*4+reg [HW-verified].
// !FINAL epilogue: LDS-stage the 64x64 tile, then quantize (bf16 + int8 rowscale tables).
template<bool FINAL>
__global__ __launch_bounds__(256) void gemm_mfma(
    const ushort* __restrict__ abf,   // bf16 [U,64] spmm result
    const ushort* __restrict__ bbf,   // bf16 [U,64] prev u
    const ushort* __restrict__ wtb,   // bf16 W^T [64,128] for this layer
    float* __restrict__ outf,         // FINAL: fp32 [U,64]
    ushort* __restrict__ outb,        // !FINAL: bf16 [U,64]
    unsigned char* __restrict__ q8,   // !FINAL: int8 [U,64]
    float* __restrict__ scale,        // !FINAL: [U]
    int U)
{
    __shared__ ushort sWt[64 * 128];  // 16 KB; reused as sOut[64][72] in epilogue
    const int t = threadIdx.x;

    for (int i = t; i < 1024; i += 256) {
        int c = i >> 4, g = i & 15;
        uint4 v = *reinterpret_cast<const uint4*>(wtb + (size_t)c * 128 + g * 8);
        int gp = g ^ (c & 7);
        *reinterpret_cast<uint4*>(&sWt[c * 128 + gp * 8]) = v;
    }
    __syncthreads();

    const int w    = t >> 6;
    const int l    = t & 63;
    const int l16  = l & 15;
    const int ksub = l >> 4;
    const int grow_base = blockIdx.x * 64 + w * 16;
    const int arow = min(grow_base + l16, U - 1);

    f32x4 acc[4] = {f32x4{0,0,0,0}, f32x4{0,0,0,0}, f32x4{0,0,0,0}, f32x4{0,0,0,0}};

    #pragma unroll
    for (int kk = 0; kk < 4; ++kk) {
        const int kof = kk * 32 + ksub * 8;
        const ushort* asrc = (kk < 2) ? (abf + ((size_t)arow << 6) + kof)
                                      : (bbf + ((size_t)arow << 6) + (kof - 64));
        bf16x8 afrag = *reinterpret_cast<const bf16x8*>(asrc);
        #pragma unroll
        for (int ct = 0; ct < 4; ++ct) {
            int c  = ct * 16 + l16;
            int g  = kk * 4 + ksub;
            int gp = g ^ (c & 7);
            bf16x8 bfrag = *reinterpret_cast<const bf16x8*>(&sWt[c * 128 + gp * 8]);
            acc[ct] = __builtin_amdgcn_mfma_f32_16x16x32_bf16(afrag, bfrag, acc[ct], 0, 0, 0);
        }
    }

    if (FINAL) {
        #pragma unroll
        for (int ct = 0; ct < 4; ++ct) {
            #pragma unroll
            for (int j = 0; j < 4; ++j) {
                int grow = grow_base + ksub * 4 + j;
                int gcol = ct * 16 + l16;
                if (grow < U) outf[((size_t)grow << 6) + gcol] = acc[ct][j];
            }
        }
    } else {
        __syncthreads();                   // sWt reads done; reuse as sOut
        ushort* sOut = sWt;                // [64][72] padded
        #pragma unroll
        for (int ct = 0; ct < 4; ++ct) {
            #pragma unroll
            for (int j = 0; j < 4; ++j) {
                int rloc = w * 16 + ksub * 4 + j;
                int col  = ct * 16 + l16;
                sOut[rloc * 72 + col] = (ushort)bf16rn(acc[ct][j]);
            }
        }
        __syncthreads();
        #pragma unroll
        for (int pass = 0; pass < 2; ++pass) {
            int rloc = pass * 32 + (t >> 3);
            int lane = t & 7;
            int grow = blockIdx.x * 64 + rloc;
            uint4 x = *reinterpret_cast<const uint4*>(&sOut[rloc * 72 + lane * 8]);
            float v0 = __uint_as_float(x.x << 16), v1 = __uint_as_float(x.x & 0xffff0000u);
            float v2 = __uint_as_float(x.y << 16), v3 = __uint_as_float(x.y & 0xffff0000u);
            float v4 = __uint_as_float(x.z << 16), v5 = __uint_as_float(x.z & 0xffff0000u);
            float v6 = __uint_as_float(x.w << 16), v7 = __uint_as_float(x.w & 0xffff0000u);
            float m = fmaxf(fmaxf(fmaxf(fabsf(v0), fabsf(v1)), fmaxf(fabsf(v2), fabsf(v3))),
                            fmaxf(fmaxf(fabsf(v4), fabsf(v5)), fmaxf(fabsf(v6), fabsf(v7))));
            m = fmaxf(m, __shfl_xor(m, 1, 8));
            m = fmaxf(m, __shfl_xor(m, 2, 8));
            m = fmaxf(m, __shfl_xor(m, 4, 8));
            float inv = (m > 1e-30f) ? 127.0f / m : 0.0f;
            unsigned b0 = (unsigned)(__float2int_rn(v0 * inv) + 128);
            unsigned b1 = (unsigned)(__float2int_rn(v1 * inv) + 128);
            unsigned b2 = (unsigned)(__float2int_rn(v2 * inv) + 128);
            unsigned b3 = (unsigned)(__float2int_rn(v3 * inv) + 128);
            unsigned b4 = (unsigned)(__float2int_rn(v4 * inv) + 128);
            unsigned b5 = (unsigned)(__float2int_rn(v5 * inv) + 128);
            unsigned b6 = (unsigned)(__float2int_rn(v6 * inv) + 128);
            unsigned b7 = (unsigned)(__float2int_rn(v7 * inv) + 128);
            uint2 pk = make_uint2(b0 | (b1 << 8) | (b2 << 16) | (b3 << 24),
                                  b4 | (b5 << 8) | (b6 << 16) | (b7 << 24));
            if (grow < U) {
                *reinterpret_cast<uint4*>(outb + ((size_t)grow << 6) + lane * 8) = x;
                reinterpret_cast<uint2*>(q8 + ((size_t)grow << 6) + lane * 8)[0] = pk;
                if (lane == 0) scale[grow] = m / 127.0f;
            }
        }
    }
}

extern "C" void kernel_launch(void* const* d_in, const int* in_sizes, int n_in,
                              void* d_out, int out_size, void* d_ws, size_t ws_size,
                              hipStream_t stream)
{
    const float* user_emb    = (const float*)d_in[0];
    const float* item_emb    = (const float*)d_in[1];
    const float* weights     = (const float*)d_in[2];
    const float* social_vals = (const float*)d_in[3];
    const float* inter_vals  = (const float*)d_in[4];
    const int*   social_rows = (const int*)d_in[5];
    const int*   social_cols = (const int*)d_in[6];
    const int*   inter_rows  = (const int*)d_in[7];
    const int*   inter_cols  = (const int*)d_in[8];

    const int D  = DD;
    const int U  = in_sizes[0] / D;
    const int I  = in_sizes[1] / D;
    const int L  = in_sizes[2] / (2 * D * D);
    const int ES = in_sizes[3];
    const int EI = in_sizes[4];

    float* out      = (float*)d_out;           // final_u [U, D]
    float* out_item = out + (size_t)U * D;     // item_emb passthrough [I, D]

    // ---- workspace layout ----
    char* p = (char*)d_ws;
    size_t off = 0;
    auto take = [&](size_t bytes) { char* r = p + off; off += align16(bytes); return r; };

    const int n2   = 2 * U;
    const int CB   = (n2 + RPCB - 1) >> CBSH;       // coarse buckets (<= 256)
    const int Etot = ES + EI;
    const int EPB  = (Etot + NBLK_P - 1) / NBLK_P;  // edges per partition block
    const int NH   = CB * NBLK_P;

    int*           row_ptr = (int*)take((size_t)(n2 + 1) * sizeof(int));
    int*           hmat    = (int*)take((size_t)NH * sizeof(int));
    int*           hS      = (int*)take((size_t)NH * sizeof(int));
    int*           bsums   = (int*)take(1024 * sizeof(int));
    unsigned*      edges   = (unsigned*)take((size_t)Etot * sizeof(unsigned));
    uint2*         bedges  = (uint2*)take((size_t)Etot * sizeof(uint2));
    ushort*        ubf     = (ushort*)take((size_t)U * D * sizeof(ushort));
    unsigned char* uq8     = (unsigned char*)take((size_t)U * D);
    float*         uscale  = (float*)take((size_t)U * sizeof(float));
    unsigned char* iq8     = (unsigned char*)take((size_t)I * D);
    float*         iscale  = (float*)take((size_t)I * sizeof(float));
    ushort*        wtb     = (ushort*)take((size_t)L * 2 * D * D * sizeof(ushort));
    ushort*        tmpA_bf = (ushort*)take((size_t)U * D * sizeof(ushort));
    ushort*        uB_bf   = (ushort*)take((size_t)U * D * sizeof(ushort));
    ushort*        uC_bf   = (ushort*)take((size_t)U * D * sizeof(ushort));
    unsigned char* uB_q8   = (unsigned char*)take((size_t)U * D);
    unsigned char* uC_q8   = (unsigned char*)take((size_t)U * D);
    float*         uB_sc   = (float*)take((size_t)U * sizeof(float));
    float*         uC_sc   = (float*)take((size_t)U * sizeof(float));

    // ---- CSR build: partition histogram -> scan (2 kernels) -> scatter -> finalize ----
    p1_hist<<<NBLK_P, 1024, 0, stream>>>(social_rows, inter_rows, hmat, ES, EI, U, CB, EPB);
    const int nb = (NH + 2047) / 2048;
    scan_partial<<<nb, 256, 0, stream>>>(hmat, hS, bsums, NH);
    scan_add2<<<(NH + 255) / 256, 256, 0, stream>>>(hS, bsums, NH);
    p2_scatter<<<NBLK_P, 1024, 0, stream>>>(
        social_rows, social_cols, social_vals,
        inter_rows, inter_cols, inter_vals,
        hS, bedges, ES, EI, U, CB, EPB);
    p3_fin<<<CB, 1024, 0, stream>>>(bedges, hS, row_ptr, edges, n2, Etot, CB);

    // ---- tables + weight transpose (one launch) ----
    const int nw = L * 2 * D * D;
    const int convthreads = (U + I) * 8 + nw;
    conv_all<<<(convthreads + 255) / 256, 256, 0, stream>>>(
        user_emb, ubf, uq8, uscale, U, item_emb, iq8, iscale, out_item, I,
        weights, wtb, nw);

    // ---- layers ----
    const int spmm_grid = ((U * 8) + 255) / 256;
    const int gemm_grid = (U + 63) / 64;
    const ushort*        uprev_bf = ubf;
    const unsigned char* uprev_q8 = uq8;
    const float*         uprev_sc = uscale;
    int which = 0;
    for (int k = 0; k < L; ++k) {
        const ushort* wk = wtb + (size_t)k * 2 * D * D;
        spmm_i8<0><<<spmm_grid, 256, 0, stream>>>(
            row_ptr, edges, uprev_q8, uprev_sc, tmpA_bf, (float*)nullptr, U);
        if (k == L - 1) {
            gemm_mfma<true><<<gemm_grid, 256, 0, stream>>>(
                tmpA_bf, uprev_bf, wk, out, (ushort*)nullptr,
                (unsigned char*)nullptr, (float*)nullptr, U);
        } else {
            ushort*        nbf = which ? uC_bf : uB_bf;
            unsigned char* nq8 = which ? uC_q8 : uB_q8;
            float*         nsc = which ? uC_sc : uB_sc;
            gemm_mfma<false><<<gemm_grid, 256, 0, stream>>>(
                tmpA_bf, uprev_bf, wk, (float*)nullptr, nbf, nq8, nsc, U);
            uprev_bf = nbf;
            uprev_q8 = nq8;
            uprev_sc = nsc;
            which ^= 1;
        }
    }

    // final_u += A_inter @ item_emb (int8 gather, fp32 accumulate into d_out)
    spmm_i8<1><<<spmm_grid, 256, 0, stream>>>(
        row_ptr + U, edges, iq8, iscale, (ushort*)nullptr, out, U);
}